// Round 5
// baseline (61.734 us; speedup 1.0000x reference)
//
#include <hip/hip_runtime.h>

// Householder reflection per row:
//   out = z - 2 * v * (v.z) / (v.v)
// B = 16384 rows, L = 2048 cols, fp32.
//
// R3: NT stores for output (write-once) -> 76 -> 60 us.  [kept]
// R4: NT loads refuted — nt bit doesn't steer L3 allocation. [reverted]
// R5: wave-per-row, ZERO barriers. One 64-lane wave owns a row:
//     32 elems/lane (8x float4 of v, 8 of z) in registers, butterfly
//     __shfl_xor reduce (all lanes get the sums, no LDS/broadcast),
//     then register-resident write. 16 dwordx4 loads in flight per
//     lane; waves fully independent -> no barrier bubble.

#define ROW_LEN 2048
#define BLOCK 256
#define ROWS_PER_BLOCK 4   // one wave per row
#define V4_PER_LANE 8      // 2048 / 4 / 64

typedef float v4f __attribute__((ext_vector_type(4)));

__global__ __launch_bounds__(BLOCK) void householder_row_kernel(
    const float* __restrict__ v,
    const float* __restrict__ z,
    float* __restrict__ out)
{
    const int wave = threadIdx.x >> 6;
    const int lane = threadIdx.x & 63;
    const int row = blockIdx.x * ROWS_PER_BLOCK + wave;
    const size_t base = (size_t)row * ROW_LEN;

    const v4f* v4 = reinterpret_cast<const v4f*>(v + base);
    const v4f* z4 = reinterpret_cast<const v4f*>(z + base);
    v4f* o4 = reinterpret_cast<v4f*>(out + base);

    // 512 float4 per row / 64 lanes = 8 each; [lane + k*64] is coalesced.
    v4f vr[V4_PER_LANE], zr[V4_PER_LANE];
    #pragma unroll
    for (int k = 0; k < V4_PER_LANE; ++k) {
        vr[k] = v4[lane + k * 64];
        zr[k] = z4[lane + k * 64];
    }

    float vz = 0.f, vv = 0.f;
    #pragma unroll
    for (int k = 0; k < V4_PER_LANE; ++k) {
        vz += vr[k].x * zr[k].x + vr[k].y * zr[k].y
            + vr[k].z * zr[k].z + vr[k].w * zr[k].w;
        vv += vr[k].x * vr[k].x + vr[k].y * vr[k].y
            + vr[k].z * vr[k].z + vr[k].w * vr[k].w;
    }

    // Butterfly reduce: every lane ends with the full-row sums.
    #pragma unroll
    for (int off = 32; off > 0; off >>= 1) {
        vz += __shfl_xor(vz, off);
        vv += __shfl_xor(vv, off);
    }

    const float s = 2.0f * vz / vv;

    #pragma unroll
    for (int k = 0; k < V4_PER_LANE; ++k) {
        v4f o = zr[k] - s * vr[k];
        // Nontemporal: don't allocate the write-once output in L2/L3.
        __builtin_nontemporal_store(o, &o4[lane + k * 64]);
    }
}

extern "C" void kernel_launch(void* const* d_in, const int* in_sizes, int n_in,
                              void* d_out, int out_size, void* d_ws, size_t ws_size,
                              hipStream_t stream) {
    const float* v = (const float*)d_in[0];
    const float* z = (const float*)d_in[1];
    float* out = (float*)d_out;

    const int B = in_sizes[0] / ROW_LEN;          // 16384 rows
    const int grid = B / ROWS_PER_BLOCK;          // 4096 blocks
    householder_row_kernel<<<grid, BLOCK, 0, stream>>>(v, z, out);
}

// Round 6
// 60.173 us; speedup vs baseline: 1.0259x; 1.0259x over previous
//
#include <hip/hip_runtime.h>

// Householder reflection per row:
//   out = z - 2 * v * (v.z) / (v.v)
// B = 16384 rows, L = 2048 cols, fp32.
// One 256-thread block per row; each thread owns 8 elements (2x float4)
// of v and z, held in registers across the reduce -> write phases so
// v and z are each read from HBM exactly once.
//
// FINAL (= R3, best measured 59.9 us):
//  - NT stores for the write-once output keep it out of L2/L3 fill path
//    (76 -> 60 us; win is contention, not bytes — FETCH unchanged).
//  - NT loads refuted (R4): nt bit doesn't steer L3 allocation on gfx950.
//  - Wave-per-row/zero-barrier refuted (R5): occupancy 78->37%, 61.7 us.
//  - Core-side 402 MB / 59.9 us = 6.7 TB/s, above the 6.29 TB/s float4
//    copy ceiling (L3 absorbs ~50% of reads). Bandwidth wall.

#define ROW_LEN 2048
#define BLOCK 256
#define WAVES (BLOCK / 64)

typedef float v4f __attribute__((ext_vector_type(4)));

__global__ __launch_bounds__(BLOCK) void householder_row_kernel(
    const float* __restrict__ v,
    const float* __restrict__ z,
    float* __restrict__ out)
{
    const int row = blockIdx.x;
    const size_t base = (size_t)row * ROW_LEN;
    const int t = threadIdx.x;

    const v4f* v4 = reinterpret_cast<const v4f*>(v + base);
    const v4f* z4 = reinterpret_cast<const v4f*>(z + base);
    v4f* o4 = reinterpret_cast<v4f*>(out + base);

    // 2048 floats = 512 float4; 256 threads -> 2 float4 each, coalesced.
    v4f va = v4[t];
    v4f vb = v4[t + BLOCK];
    v4f za = z4[t];
    v4f zb = z4[t + BLOCK];

    float vz = va.x * za.x + va.y * za.y + va.z * za.z + va.w * za.w
             + vb.x * zb.x + vb.y * zb.y + vb.z * zb.z + vb.w * zb.w;
    float vv = va.x * va.x + va.y * va.y + va.z * va.z + va.w * va.w
             + vb.x * vb.x + vb.y * vb.y + vb.z * vb.z + vb.w * vb.w;

    // Wave-level reduce across 64 lanes.
    #pragma unroll
    for (int off = 32; off > 0; off >>= 1) {
        vz += __shfl_down(vz, off);
        vv += __shfl_down(vv, off);
    }

    __shared__ float svz[WAVES];
    __shared__ float svv[WAVES];

    const int wave = t >> 6;
    const int lane = t & 63;
    if (lane == 0) { svz[wave] = vz; svv[wave] = vv; }
    __syncthreads();

    // All threads sum the 4 per-wave partials (broadcast reads, no conflict).
    float tvz = 0.f, tvv = 0.f;
    #pragma unroll
    for (int w = 0; w < WAVES; ++w) { tvz += svz[w]; tvv += svv[w]; }
    const float s = 2.0f * tvz / tvv;

    v4f oa = za - s * va;
    v4f ob = zb - s * vb;

    // Nontemporal: don't allocate the write-once output in L2/L3.
    __builtin_nontemporal_store(oa, &o4[t]);
    __builtin_nontemporal_store(ob, &o4[t + BLOCK]);
}

extern "C" void kernel_launch(void* const* d_in, const int* in_sizes, int n_in,
                              void* d_out, int out_size, void* d_ws, size_t ws_size,
                              hipStream_t stream) {
    const float* v = (const float*)d_in[0];
    const float* z = (const float*)d_in[1];
    float* out = (float*)d_out;

    const int B = in_sizes[0] / ROW_LEN;  // 16384
    householder_row_kernel<<<B, BLOCK, 0, stream>>>(v, z, out);
}